// Round 5
// baseline (242.664 us; speedup 1.0000x reference)
//
#include <hip/hip_runtime.h>

// ---------------------------------------------------------------------------
// Self-attention: out = softmax((xWq)(xWk)^T / sqrt(64)) (xWv)
// B=4, N=4096, Din=128, Dout=64.
//   k0 wprep  : W (98KB fp32) -> hi/lo bf16 planes in MFMA B-frag order,
//               Q-scale (0.125*log2e) folded into plane 0.
//   k1 qkv    : x@W via 3-pass bf16 MFMA. W frags direct from L2 (no W LDS,
//               no staging VALU). Outputs: Qhi/Qlo, Khi/Klo row-major,
//               V in B-frag global layout (Vb). Epilogue LDS transpose.
//   k2 attn   : flash attention, 32-q waves (4/block), 4 waves/SIMD target.
//               K hi/lo double-buffered in LDS (3-pass S, fp32-accurate);
//               V direct-from-global B-frags (coalesced, L2-hot); P C->A
//               layout via shfl_xor(32); online softmax base-2.
//   k3 merge  : combine nseg segment partials (bf16 O partials).
// nseg = 16 if workspace allows (~46 MB), else 8.
// ---------------------------------------------------------------------------

typedef __attribute__((ext_vector_type(8))) short bf16x8;
typedef __attribute__((ext_vector_type(16))) float f32x16;
typedef __attribute__((ext_vector_type(4))) unsigned u32x4;
typedef unsigned short us;

__device__ __forceinline__ us f2bf(float f) {               // RTNE fp32->bf16
  unsigned u = __builtin_bit_cast(unsigned, f);
  u += 0x7FFFu + ((u >> 16) & 1u);
  return (us)(u >> 16);
}
__device__ __forceinline__ float bf2f(us h) {
  unsigned u = ((unsigned)h) << 16;
  return __builtin_bit_cast(float, u);
}
__device__ __forceinline__ f32x16 mfma(bf16x8 a, bf16x8 b, f32x16 c) {
  return __builtin_amdgcn_mfma_f32_32x32x16_bf16(a, b, c, 0, 0, 0);
}
__device__ __forceinline__ unsigned pk2(float a, float b) {
  return (unsigned)f2bf(a) | ((unsigned)f2bf(b) << 16);
}
#define EXP2(x) __builtin_amdgcn_exp2f(x)

// ---------------------------------------------------------------------------
// Kernel 0: W prep. w[3][128][64] fp32 -> Wbh/Wbl (bf16 hi/lo) in B-frag
// order: idx = ((g*8+ks)*2+h)*256 + (e&31)*8 + j, g = (p*64+e)>>5,
// ks=d>>4, h=(d>>3)&1, j=d&7. Plane p==0 pre-scaled by 0.125*log2(e).
// ---------------------------------------------------------------------------
__global__ __launch_bounds__(256, 1) void wprep_kernel(
    const float* __restrict__ w, us* __restrict__ Wbh, us* __restrict__ Wbl)
{
  const int i = blockIdx.x * 256 + threadIdx.x;
  if (i >= 24576) return;
  const int p = i >> 13, d = (i & 8191) >> 6, e = i & 63;
  float v = w[i];
  if (p == 0) v *= 0.18033688011112042f;
  const us hi = f2bf(v);
  const us lo = f2bf(v - bf2f(hi));
  const int g = (p * 64 + e) >> 5, ks = d >> 4, hh = (d >> 3) & 1, j = d & 7;
  const int o = ((g * 8 + ks) * 2 + hh) * 256 + (e & 31) * 8 + j;
  Wbh[o] = hi;
  Wbl[o] = lo;
}

// ---------------------------------------------------------------------------
// Kernel 1: QKV projection. 256 blocks x 256 thr; block = 128 rows x 96 cols
// (ch halves). W frags loaded straight from Wbh/Wbl (L2-hot, coalesced).
// ---------------------------------------------------------------------------
#define TP 101  // transpose tile pitch (uints)

__global__ __launch_bounds__(256, 1) void qkv_kernel(
    const float* __restrict__ x,
    const us* __restrict__ Wbh, const us* __restrict__ Wbl,
    us* __restrict__ Qhi, us* __restrict__ Qlo,
    us* __restrict__ Khi, us* __restrict__ Klo, us* __restrict__ Vb)
{
  __shared__ unsigned ttile[128 * TP];   // 51,712 B
  const int t = threadIdx.x;
  const int rb = blockIdx.x >> 1, ch = blockIdx.x & 1;
  const int wid = t >> 6, lane = t & 63;
  const int l31 = lane & 31, h = lane >> 5;
  const int rbase = rb * 128 + wid * 32;
  const float* xrow = x + (size_t)(rbase + l31) * 128;

  f32x16 acc[3] = {};
  #pragma unroll
  for (int ks = 0; ks < 8; ++ks) {           // K = 128 = 8 * 16
    const int d0 = ks * 16 + h * 8;
    const float4 xa = *(const float4*)(xrow + d0);
    const float4 xb = *(const float4*)(xrow + d0 + 4);
    const float xv[8] = {xa.x, xa.y, xa.z, xa.w, xb.x, xb.y, xb.z, xb.w};
    bf16x8 ah, al;
    #pragma unroll
    for (int j = 0; j < 8; ++j) {
      us hi = f2bf(xv[j]);
      ah[j] = (short)hi;
      al[j] = (short)f2bf(xv[j] - bf2f(hi));
    }
    #pragma unroll
    for (int nt = 0; nt < 3; ++nt) {
      const int g = ch * 3 + nt;
      const int wo = ((g * 8 + ks) * 2 + h) * 256 + l31 * 8;
      bf16x8 bh = *(const bf16x8*)(Wbh + wo);
      bf16x8 bl = *(const bf16x8*)(Wbl + wo);
      acc[nt] = mfma(ah, bh, acc[nt]);
      acc[nt] = mfma(al, bh, acc[nt]);
      acc[nt] = mfma(ah, bl, acc[nt]);
    }
  }

  // pack hi|lo into transpose tile. C layout: row=(r&3)+8*(r>>2)+4h, col=l31+32nt
  #pragma unroll
  for (int nt = 0; nt < 3; ++nt) {
    const int col = 32 * nt + l31;
    #pragma unroll
    for (int r = 0; r < 16; ++r) {
      const int rl = (r & 3) + 8 * (r >> 2) + 4 * h;
      float v = acc[nt][r];
      us hi = f2bf(v);
      us lo = f2bf(v - bf2f(hi));
      ttile[(wid * 32 + rl) * TP + col] = (unsigned)hi | ((unsigned)lo << 16);
    }
  }
  __syncthreads();

  // coalesced store phase
  const int row = t >> 1;
  const int grow = rb * 128 + row;
  if (ch == 0) {
    {  // Q: local cols 0..63
      const int cb = (t & 1) * 32;
      unsigned hw[16], lw[16];
      #pragma unroll
      for (int j = 0; j < 16; ++j) {
        unsigned a = ttile[row * TP + cb + 2 * j];
        unsigned bv = ttile[row * TP + cb + 2 * j + 1];
        hw[j] = (a & 0xffffu) | (bv << 16);
        lw[j] = (a >> 16) | (bv & 0xffff0000u);
      }
      #pragma unroll
      for (int j = 0; j < 4; ++j) {
        uint4 hv = {hw[4 * j], hw[4 * j + 1], hw[4 * j + 2], hw[4 * j + 3]};
        uint4 lv = {lw[4 * j], lw[4 * j + 1], lw[4 * j + 2], lw[4 * j + 3]};
        *(uint4*)(Qhi + (size_t)grow * 64 + cb + 8 * j) = hv;
        *(uint4*)(Qlo + (size_t)grow * 64 + cb + 8 * j) = lv;
      }
    }
    {  // K: local cols 64..95 -> e 0..31
      const int cs = (t & 1) * 16;
      unsigned hw[8], lw[8];
      #pragma unroll
      for (int j = 0; j < 8; ++j) {
        unsigned a = ttile[row * TP + 64 + cs + 2 * j];
        unsigned bv = ttile[row * TP + 64 + cs + 2 * j + 1];
        hw[j] = (a & 0xffffu) | (bv << 16);
        lw[j] = (a >> 16) | (bv & 0xffff0000u);
      }
      #pragma unroll
      for (int j = 0; j < 2; ++j) {
        uint4 hv = {hw[4 * j], hw[4 * j + 1], hw[4 * j + 2], hw[4 * j + 3]};
        uint4 lv = {lw[4 * j], lw[4 * j + 1], lw[4 * j + 2], lw[4 * j + 3]};
        *(uint4*)(Khi + (size_t)grow * 64 + cs + 8 * j) = hv;
        *(uint4*)(Klo + (size_t)grow * 64 + cs + 8 * j) = lv;
      }
    }
  } else {
    {  // K: local cols 0..31 -> e 32..63
      const int cs = (t & 1) * 16;
      unsigned hw[8], lw[8];
      #pragma unroll
      for (int j = 0; j < 8; ++j) {
        unsigned a = ttile[row * TP + cs + 2 * j];
        unsigned bv = ttile[row * TP + cs + 2 * j + 1];
        hw[j] = (a & 0xffffu) | (bv << 16);
        lw[j] = (a >> 16) | (bv & 0xffff0000u);
      }
      #pragma unroll
      for (int j = 0; j < 2; ++j) {
        uint4 hv = {hw[4 * j], hw[4 * j + 1], hw[4 * j + 2], hw[4 * j + 3]};
        uint4 lv = {lw[4 * j], lw[4 * j + 1], lw[4 * j + 2], lw[4 * j + 3]};
        *(uint4*)(Khi + (size_t)grow * 64 + 32 + cs + 8 * j) = hv;
        *(uint4*)(Klo + (size_t)grow * 64 + 32 + cs + 8 * j) = lv;
      }
    }
    {  // V: local cols 32..95 -> Vb B-frag layout
      const int bb = (rb * 128) >> 12;
      const int nb = (rb * 128) & 4095;
      #pragma unroll
      for (int i2 = 0; i2 < 4; ++i2) {
        const int c = t + 256 * i2;
        const int e = c >> 4, nc = c & 15;
        unsigned p[4];
        #pragma unroll
        for (int j = 0; j < 4; ++j) {
          unsigned a = ttile[(nc * 8 + 2 * j) * TP + 32 + e];
          unsigned bv = ttile[(nc * 8 + 2 * j + 1) * TP + 32 + e];
          p[j] = (a & 0xffffu) | (bv << 16);
        }
        uint4 pv = {p[0], p[1], p[2], p[3]};
        const int n0 = nb + nc * 8;
        const int kt = n0 >> 6, sub = n0 & 63;
        const int ks = sub >> 4, hh = (sub >> 3) & 1;
        const int dt = e >> 5, lv = e & 31;
        *(uint4*)(Vb + (size_t)bb * 262144 +
                  ((((kt * 4 + ks) * 2 + hh) * 2 + dt) * 256 + lv * 8)) = pv;
      }
    }
  }
}

// ---------------------------------------------------------------------------
// Kernel 2: flash attention partials. Blocks of 4 waves; WAVE = 32 queries
// (halved state -> ~128 regs -> 4 waves/SIMD). K hi/lo double-buffered in
// LDS (XOR-swizzled); V read direct from Vb global B-frags at PV.
// ---------------------------------------------------------------------------
__global__ __launch_bounds__(256, 4) void attn_kernel(
    const us* __restrict__ Qhi, const us* __restrict__ Qlo,
    const us* __restrict__ Khi, const us* __restrict__ Klo,
    const us* __restrict__ Vb,
    us* __restrict__ Opart, float* __restrict__ Mpart,
    float* __restrict__ Lpart, int nseg_sh, int iters)
{
  __shared__ union {
    struct { us kh[2][4096]; us kl[2][4096]; } tl;  // 32,768 B
    float fb[4][2112];                              // 33,792 B (epilogue)
  } sm;
  __shared__ float alds[4][32];

  // XCD-aware map: XCD x serves batch x>>1
  const int bx = blockIdx.x;
  const int xc = bx & 7, b = xc >> 1;
  const int idx = ((bx >> 3) << 1) | (xc & 1);    // 0 .. 32*nseg-1
  const int nseg = 1 << nseg_sh;
  const int seg = idx & (nseg - 1), qg = idx >> nseg_sh;  // qg 0..31
  const int t = threadIdx.x;
  const int wid = t >> 6, lane = t & 63;
  const int l31 = lane & 31, h = lane >> 5;
  const int q0 = qg * 128 + wid * 32;             // wave's first q
  const int u = (b * 4096 + q0) >> 5;             // global 32q unit, 0..511
  const size_t pb = (size_t)u * nseg + seg;

  // persistent Q B-frags: n=l31, k=16ks+8h+j
  bf16x8 qh[4], ql[4];
  {
    const size_t rg = (size_t)(b * 4096 + q0 + l31) * 64;
    #pragma unroll
    for (int ks = 0; ks < 4; ++ks) {
      qh[ks] = *(const bf16x8*)(Qhi + rg + ks * 16 + h * 8);
      ql[ks] = *(const bf16x8*)(Qlo + rg + ks * 16 + h * 8);
    }
  }
  const size_t kbase = (size_t)b * 262144;
  const size_t vbb = (size_t)b * 262144;

  // staging map: thread t -> rows (t>>3, t>>3+32), 16B slot (t&7), XOR swizzle
  const int row0 = t >> 3, slot = t & 7;
  const int gcol = (slot ^ (row0 & 7)) * 8;
  const int ld0 = row0 * 64 + slot * 8;
  const int ld1 = ld0 + 2048;

  // prologue: tile 0 -> buffer 0
  {
    const int k0 = seg * iters * 64;
    *(bf16x8*)(&sm.tl.kh[0][ld0]) = *(const bf16x8*)(Khi + kbase + (size_t)(k0 + row0) * 64 + gcol);
    *(bf16x8*)(&sm.tl.kh[0][ld1]) = *(const bf16x8*)(Khi + kbase + (size_t)(k0 + row0 + 32) * 64 + gcol);
    *(bf16x8*)(&sm.tl.kl[0][ld0]) = *(const bf16x8*)(Klo + kbase + (size_t)(k0 + row0) * 64 + gcol);
    *(bf16x8*)(&sm.tl.kl[0][ld1]) = *(const bf16x8*)(Klo + kbase + (size_t)(k0 + row0 + 32) * 64 + gcol);
  }
  __syncthreads();

  f32x16 o[2] = {};
  float mrun = -__builtin_inff();
  float lrun = 0.f;

  for (int it = 0; it < iters; ++it) {
    const int cur = it & 1, nxt = cur ^ 1;
    const int KT = seg * iters + it;              // global 64-key tile id

    // prefetch next K tile into regs
    const int itn = (it + 1 < iters) ? it + 1 : it;
    const int nk = (seg * iters + itn) * 64;
    bf16x8 nk0 = *(const bf16x8*)(Khi + kbase + (size_t)(nk + row0) * 64 + gcol);
    bf16x8 nk1 = *(const bf16x8*)(Khi + kbase + (size_t)(nk + row0 + 32) * 64 + gcol);
    bf16x8 nl0 = *(const bf16x8*)(Klo + kbase + (size_t)(nk + row0) * 64 + gcol);
    bf16x8 nl1 = *(const bf16x8*)(Klo + kbase + (size_t)(nk + row0 + 32) * 64 + gcol);

    // S^T = K_tile · Q^T (3-pass hi/lo): s[m] C-layout rows=keys, cols=q
    f32x16 s[2] = {};
    #pragma unroll
    for (int m = 0; m < 2; ++m) {
      const int krow = 32 * m + l31;
      #pragma unroll
      for (int ks = 0; ks < 4; ++ks) {
        const int off = krow * 64 + (((2 * ks + h) ^ (l31 & 7)) * 8);
        bf16x8 ah = *(const bf16x8*)(&sm.tl.kh[cur][off]);
        bf16x8 al = *(const bf16x8*)(&sm.tl.kl[cur][off]);
        s[m] = mfma(ah, qh[ks], s[m]);
        s[m] = mfma(al, qh[ks], s[m]);
        s[m] = mfma(ah, ql[ks], s[m]);
      }
    }

    // stage prefetched K into other buffer (no reader until barrier)
    *(bf16x8*)(&sm.tl.kh[nxt][ld0]) = nk0;
    *(bf16x8*)(&sm.tl.kh[nxt][ld1]) = nk1;
    *(bf16x8*)(&sm.tl.kl[nxt][ld0]) = nl0;
    *(bf16x8*)(&sm.tl.kl[nxt][ld1]) = nl1;

    // online softmax (base-2; scale folded into Q). Lane owns q=l31; holds
    // 32 of its 64 key-scores, partner (xor 32) the rest.
    float vm = -__builtin_inff();
    #pragma unroll
    for (int r = 0; r < 16; ++r)
      vm = fmaxf(vm, fmaxf(s[0][r], s[1][r]));
    vm = fmaxf(vm, __shfl_xor(vm, 32));
    const float mnew = fmaxf(mrun, vm);
    const float alpha = EXP2(mrun - mnew);
    float sum = 0.f;
    unsigned pp[2][8];
    #pragma unroll
    for (int m = 0; m < 2; ++m) {
      #pragma unroll
      for (int p = 0; p < 8; ++p) {
        const float p0 = EXP2(s[m][2 * p] - mnew);
        const float p1 = EXP2(s[m][2 * p + 1] - mnew);
        sum += p0 + p1;
        pp[m][p] = pk2(p0, p1);
      }
    }
    sum += __shfl_xor(sum, 32);
    lrun = lrun * alpha + sum;
    mrun = mnew;

    // rescale O (skip when all-ones; alds broadcast to C-layout rows)
    if (__any(alpha != 1.f)) {
      if (!h) alds[wid][l31] = alpha;
      #pragma unroll
      for (int g = 0; g < 4; ++g) {
        const float4 af4 = *(const float4*)(&alds[wid][8 * g + 4 * h]);
        #pragma unroll
        for (int rr = 0; rr < 4; ++rr) {
          const int r = 4 * g + rr;
          const float a = (rr == 0) ? af4.x : (rr == 1) ? af4.y
                         : (rr == 2) ? af4.z : af4.w;
          o[0][r] *= a;
          o[1][r] *= a;
        }
      }
    }

    // PV: P A-frags via shfl_xor(32) pair exchange; V B-frags from global.
    #pragma unroll
    for (int ks = 0; ks < 4; ++ks) {
      const int m = ks >> 1, base = 4 * (ks & 1);
      const unsigned x0 = pp[m][base + 0], x1 = pp[m][base + 1];
      const unsigned x2 = pp[m][base + 2], x3 = pp[m][base + 3];
      const unsigned sA = h ? x0 : x2;
      const unsigned sB = h ? x1 : x3;
      const unsigned rA = (unsigned)__shfl_xor((int)sA, 32);
      const unsigned rB = (unsigned)__shfl_xor((int)sB, 32);
      u32x4 wv;
      wv.x = h ? rA : x0;
      wv.y = h ? rB : x1;
      wv.z = h ? x2 : rA;
      wv.w = h ? x3 : rB;
      const bf16x8 af = __builtin_bit_cast(bf16x8, wv);
      const size_t vo = vbb + (size_t)((((KT * 4 + ks) * 2 + h) * 2) * 256 + l31 * 8);
      const bf16x8 vf0 = *(const bf16x8*)(Vb + vo);
      const bf16x8 vf1 = *(const bf16x8*)(Vb + vo + 256);
      o[0] = mfma(af, vf0, o[0]);
      o[1] = mfma(af, vf1, o[1]);
    }

    __syncthreads();  // cur reads done everywhere; nxt staging visible
  }

  // epilogue: O -> bf16 Opart via per-wave LDS bounce, dwordx4 stores.
  float* fb = sm.fb[wid];
  #pragma unroll
  for (int dt = 0; dt < 2; ++dt) {
    #pragma unroll
    for (int r = 0; r < 16; ++r) {
      const int qrow = (r & 3) + 8 * (r >> 2) + 4 * h;  // 0..31
      fb[qrow * 66 + l31 + 32 * dt] = o[dt][r];
    }
  }
  #pragma unroll
  for (int jj = 0; jj < 4; ++jj) {
    const int chunk = lane + 64 * jj;         // 0..255
    const int rw = chunk >> 3, part = chunk & 7;
    const float* src = &fb[rw * 66 + part * 8];
    float2 a0 = *(const float2*)(src + 0);
    float2 a1 = *(const float2*)(src + 2);
    float2 a2 = *(const float2*)(src + 4);
    float2 a3 = *(const float2*)(src + 6);
    uint4 pkv;
    pkv.x = pk2(a0.x, a0.y);
    pkv.y = pk2(a1.x, a1.y);
    pkv.z = pk2(a2.x, a2.y);
    pkv.w = pk2(a3.x, a3.y);
    *(uint4*)(Opart + pb * 2048 + (size_t)rw * 64 + part * 8) = pkv;
  }
  if (!h) {
    Mpart[pb * 32 + l31] = mrun;
    Lpart[pb * 32 + l31] = lrun;
  }
}

// ---------------------------------------------------------------------------
// Kernel 3: merge nseg key-segment partials (bf16). 131072 thr, 8 d each.
// ---------------------------------------------------------------------------
__global__ __launch_bounds__(256, 1) void merge_kernel(
    const us* __restrict__ Opart, const float* __restrict__ Mpart,
    const float* __restrict__ Lpart, float* __restrict__ out, int nseg)
{
  const int tg = blockIdx.x * 256 + threadIdx.x;
  const int q = tg >> 3, dc = (tg & 7) * 8;
  const int u = q >> 5, ql = q & 31;
  const int base = u * nseg;
  float M = -__builtin_inff();
  for (int s = 0; s < nseg; ++s)
    M = fmaxf(M, Mpart[(size_t)(base + s) * 32 + ql]);
  float acc[8] = {};
  float den = 0.f;
  for (int s = 0; s < nseg; ++s) {
    const float wgt = EXP2(Mpart[(size_t)(base + s) * 32 + ql] - M);
    den += wgt * Lpart[(size_t)(base + s) * 32 + ql];
    const uint4 r = *(const uint4*)(Opart + (size_t)(base + s) * 2048 +
                                    ql * 64 + dc);
    const unsigned rw[4] = {r.x, r.y, r.z, r.w};
    #pragma unroll
    for (int j = 0; j < 4; ++j) {
      acc[2 * j]     += wgt * bf2f((us)(rw[j] & 0xffffu));
      acc[2 * j + 1] += wgt * bf2f((us)(rw[j] >> 16));
    }
  }
  const float inv = 1.f / den;
  float4 r0 = {acc[0] * inv, acc[1] * inv, acc[2] * inv, acc[3] * inv};
  float4 r1 = {acc[4] * inv, acc[5] * inv, acc[6] * inv, acc[7] * inv};
  *(float4*)(out + (size_t)q * 64 + dc) = r0;
  *(float4*)(out + (size_t)q * 64 + dc + 4) = r1;
}

// ---------------------------------------------------------------------------
extern "C" void kernel_launch(void* const* d_in, const int* in_sizes, int n_in,
                              void* d_out, int out_size, void* d_ws,
                              size_t ws_size, hipStream_t stream)
{
  const float* x = (const float*)d_in[0];
  const float* w = (const float*)d_in[1];
  float* out = (float*)d_out;
  char* ws = (char*)d_ws;

  const size_t T = 2097152;  // bytes per bf16 [4,4096,64] tensor
  us* Qhi = (us*)(ws + 0 * T);
  us* Qlo = (us*)(ws + 1 * T);
  us* Khi = (us*)(ws + 2 * T);
  us* Klo = (us*)(ws + 3 * T);
  us* Vb  = (us*)(ws + 4 * T);
  us* Wbh = (us*)(ws + 5 * T);                    // 49,152 B
  us* Wbl = (us*)(ws + 5 * T + 49152);            // 49,152 B
  char* pbase = ws + 5 * T + 98304;               // 10,584,064

  // nseg = 16 needs ~46.3 MB total; fall back to 8 (~29 MB) if tight.
  const int nseg_sh = (ws_size >= (47ull << 20)) ? 4 : 3;
  const int nseg = 1 << nseg_sh;
  const int iters = 64 >> nseg_sh;                // 64-key tiles per segment
  us* Opart = (us*)pbase;                                    // nseg*2 MiB
  float* Mpart = (float*)(pbase + (size_t)nseg * 2097152);   // nseg*64 KiB
  float* Lpart = (float*)(pbase + (size_t)nseg * 2097152 +
                          (size_t)nseg * 65536);

  hipLaunchKernelGGL(wprep_kernel, dim3(96), dim3(256), 0, stream, w, Wbh, Wbl);
  hipLaunchKernelGGL(qkv_kernel, dim3(256), dim3(256), 0, stream,
                     x, Wbh, Wbl, Qhi, Qlo, Khi, Klo, Vb);
  hipLaunchKernelGGL(attn_kernel, dim3(128 * nseg), dim3(256), 0, stream,
                     Qhi, Qlo, Khi, Klo, Vb, Opart, Mpart, Lpart,
                     nseg_sh, iters);
  hipLaunchKernelGGL(merge_kernel, dim3(512), dim3(256), 0, stream,
                     Opart, Mpart, Lpart, out, nseg);
}

// Round 6
// 137.466 us; speedup vs baseline: 1.7653x; 1.7653x over previous
//
#include <hip/hip_runtime.h>

// ---------------------------------------------------------------------------
// Self-attention: out = softmax((xWq)(xWk)^T / sqrt(64)) (xWv)
// B=4, N=4096, Din=128, Dout=64.
//   k0 wprep  : W -> hi/lo bf16 planes in MFMA B-frag order (Q-scale folded).
//   k1 qkv    : x@W via 3-pass bf16 MFMA, W frags direct from L2.
//               Outputs Qhi/Qlo, Khi/Klo row-major, V in B-frag layout (Vb).
//   k2 attn   : flash attention, 32-q waves (4/block), nseg=8 (512 keys/seg).
//               K hi/lo double-buffered in LDS via async global_load_lds
//               (width 16, no staging VGPRs); V direct-from-global B-frags;
//               P C->A via shfl_xor(32); online softmax base-2; 3-pass S.
//               __launch_bounds__(256,3): cap ~170 regs -> NO SPILL (round-5
//               lesson: (256,4) spilled -> 700 MB scratch traffic).
//   k3 merge  : combine 8 segment partials (bf16 O partials).
// ---------------------------------------------------------------------------

typedef __attribute__((ext_vector_type(8))) short bf16x8;
typedef __attribute__((ext_vector_type(16))) float f32x16;
typedef __attribute__((ext_vector_type(4))) unsigned u32x4;
typedef unsigned short us;

__device__ __forceinline__ us f2bf(float f) {               // RTNE fp32->bf16
  unsigned u = __builtin_bit_cast(unsigned, f);
  u += 0x7FFFu + ((u >> 16) & 1u);
  return (us)(u >> 16);
}
__device__ __forceinline__ float bf2f(us h) {
  unsigned u = ((unsigned)h) << 16;
  return __builtin_bit_cast(float, u);
}
__device__ __forceinline__ f32x16 mfma(bf16x8 a, bf16x8 b, f32x16 c) {
  return __builtin_amdgcn_mfma_f32_32x32x16_bf16(a, b, c, 0, 0, 0);
}
__device__ __forceinline__ unsigned pk2(float a, float b) {
  return (unsigned)f2bf(a) | ((unsigned)f2bf(b) << 16);
}
#define EXP2(x) __builtin_amdgcn_exp2f(x)

// async 16B global->LDS DMA: lane i of the wave lands at ldsbase + 16*i
__device__ __forceinline__ void gld16(const us* g, us* l) {
  __builtin_amdgcn_global_load_lds(
      (__attribute__((address_space(1))) const unsigned int*)g,
      (__attribute__((address_space(3))) unsigned int*)l, 16, 0, 0);
}

// ---------------------------------------------------------------------------
// Kernel 0: W prep. w[3][128][64] fp32 -> Wbh/Wbl bf16 hi/lo, B-frag order:
// idx = ((g*8+ks)*2+h)*256 + (e&31)*8 + j ; g=(p*64+e)>>5, ks=d>>4,
// h=(d>>3)&1, j=d&7. Plane p==0 pre-scaled by 0.125*log2(e).
// ---------------------------------------------------------------------------
__global__ __launch_bounds__(256, 1) void wprep_kernel(
    const float* __restrict__ w, us* __restrict__ Wbh, us* __restrict__ Wbl)
{
  const int i = blockIdx.x * 256 + threadIdx.x;
  if (i >= 24576) return;
  const int p = i >> 13, d = (i & 8191) >> 6, e = i & 63;
  float v = w[i];
  if (p == 0) v *= 0.18033688011112042f;
  const us hi = f2bf(v);
  const us lo = f2bf(v - bf2f(hi));
  const int g = (p * 64 + e) >> 5, ks = d >> 4, hh = (d >> 3) & 1, j = d & 7;
  const int o = ((g * 8 + ks) * 2 + hh) * 256 + (e & 31) * 8 + j;
  Wbh[o] = hi;
  Wbl[o] = lo;
}

// ---------------------------------------------------------------------------
// Kernel 1: QKV projection. 256 blocks x 256 thr; block = 128 rows x 96 cols.
// ---------------------------------------------------------------------------
#define TP 101  // transpose tile pitch (uints)

__global__ __launch_bounds__(256, 1) void qkv_kernel(
    const float* __restrict__ x,
    const us* __restrict__ Wbh, const us* __restrict__ Wbl,
    us* __restrict__ Qhi, us* __restrict__ Qlo,
    us* __restrict__ Khi, us* __restrict__ Klo, us* __restrict__ Vb)
{
  __shared__ unsigned ttile[128 * TP];   // 51,712 B
  const int t = threadIdx.x;
  const int rb = blockIdx.x >> 1, ch = blockIdx.x & 1;
  const int wid = t >> 6, lane = t & 63;
  const int l31 = lane & 31, h = lane >> 5;
  const int rbase = rb * 128 + wid * 32;
  const float* xrow = x + (size_t)(rbase + l31) * 128;

  f32x16 acc[3] = {};
  #pragma unroll
  for (int ks = 0; ks < 8; ++ks) {           // K = 128 = 8 * 16
    const int d0 = ks * 16 + h * 8;
    const float4 xa = *(const float4*)(xrow + d0);
    const float4 xb = *(const float4*)(xrow + d0 + 4);
    const float xv[8] = {xa.x, xa.y, xa.z, xa.w, xb.x, xb.y, xb.z, xb.w};
    bf16x8 ah, al;
    #pragma unroll
    for (int j = 0; j < 8; ++j) {
      us hi = f2bf(xv[j]);
      ah[j] = (short)hi;
      al[j] = (short)f2bf(xv[j] - bf2f(hi));
    }
    #pragma unroll
    for (int nt = 0; nt < 3; ++nt) {
      const int g = ch * 3 + nt;
      const int wo = ((g * 8 + ks) * 2 + h) * 256 + l31 * 8;
      bf16x8 bh = *(const bf16x8*)(Wbh + wo);
      bf16x8 bl = *(const bf16x8*)(Wbl + wo);
      acc[nt] = mfma(ah, bh, acc[nt]);
      acc[nt] = mfma(al, bh, acc[nt]);
      acc[nt] = mfma(ah, bl, acc[nt]);
    }
  }

  // pack hi|lo into transpose tile. C layout: row=(r&3)+8*(r>>2)+4h
  #pragma unroll
  for (int nt = 0; nt < 3; ++nt) {
    const int col = 32 * nt + l31;
    #pragma unroll
    for (int r = 0; r < 16; ++r) {
      const int rl = (r & 3) + 8 * (r >> 2) + 4 * h;
      float v = acc[nt][r];
      us hi = f2bf(v);
      us lo = f2bf(v - bf2f(hi));
      ttile[(wid * 32 + rl) * TP + col] = (unsigned)hi | ((unsigned)lo << 16);
    }
  }
  __syncthreads();

  // coalesced store phase
  const int row = t >> 1;
  const int grow = rb * 128 + row;
  if (ch == 0) {
    {  // Q: local cols 0..63
      const int cb = (t & 1) * 32;
      unsigned hw[16], lw[16];
      #pragma unroll
      for (int j = 0; j < 16; ++j) {
        unsigned a = ttile[row * TP + cb + 2 * j];
        unsigned bv = ttile[row * TP + cb + 2 * j + 1];
        hw[j] = (a & 0xffffu) | (bv << 16);
        lw[j] = (a >> 16) | (bv & 0xffff0000u);
      }
      #pragma unroll
      for (int j = 0; j < 4; ++j) {
        uint4 hv = {hw[4 * j], hw[4 * j + 1], hw[4 * j + 2], hw[4 * j + 3]};
        uint4 lv = {lw[4 * j], lw[4 * j + 1], lw[4 * j + 2], lw[4 * j + 3]};
        *(uint4*)(Qhi + (size_t)grow * 64 + cb + 8 * j) = hv;
        *(uint4*)(Qlo + (size_t)grow * 64 + cb + 8 * j) = lv;
      }
    }
    {  // K: local cols 64..95 -> e 0..31
      const int cs = (t & 1) * 16;
      unsigned hw[8], lw[8];
      #pragma unroll
      for (int j = 0; j < 8; ++j) {
        unsigned a = ttile[row * TP + 64 + cs + 2 * j];
        unsigned bv = ttile[row * TP + 64 + cs + 2 * j + 1];
        hw[j] = (a & 0xffffu) | (bv << 16);
        lw[j] = (a >> 16) | (bv & 0xffff0000u);
      }
      #pragma unroll
      for (int j = 0; j < 2; ++j) {
        uint4 hv = {hw[4 * j], hw[4 * j + 1], hw[4 * j + 2], hw[4 * j + 3]};
        uint4 lv = {lw[4 * j], lw[4 * j + 1], lw[4 * j + 2], lw[4 * j + 3]};
        *(uint4*)(Khi + (size_t)grow * 64 + cs + 8 * j) = hv;
        *(uint4*)(Klo + (size_t)grow * 64 + cs + 8 * j) = lv;
      }
    }
  } else {
    {  // K: local cols 0..31 -> e 32..63
      const int cs = (t & 1) * 16;
      unsigned hw[8], lw[8];
      #pragma unroll
      for (int j = 0; j < 8; ++j) {
        unsigned a = ttile[row * TP + cs + 2 * j];
        unsigned bv = ttile[row * TP + cs + 2 * j + 1];
        hw[j] = (a & 0xffffu) | (bv << 16);
        lw[j] = (a >> 16) | (bv & 0xffff0000u);
      }
      #pragma unroll
      for (int j = 0; j < 2; ++j) {
        uint4 hv = {hw[4 * j], hw[4 * j + 1], hw[4 * j + 2], hw[4 * j + 3]};
        uint4 lv = {lw[4 * j], lw[4 * j + 1], lw[4 * j + 2], lw[4 * j + 3]};
        *(uint4*)(Khi + (size_t)grow * 64 + 32 + cs + 8 * j) = hv;
        *(uint4*)(Klo + (size_t)grow * 64 + 32 + cs + 8 * j) = lv;
      }
    }
    {  // V: local cols 32..95 -> Vb B-frag layout
      const int bb = (rb * 128) >> 12;
      const int nb = (rb * 128) & 4095;
      #pragma unroll
      for (int i2 = 0; i2 < 4; ++i2) {
        const int c = t + 256 * i2;
        const int e = c >> 4, nc = c & 15;
        unsigned p[4];
        #pragma unroll
        for (int j = 0; j < 4; ++j) {
          unsigned a = ttile[(nc * 8 + 2 * j) * TP + 32 + e];
          unsigned bv = ttile[(nc * 8 + 2 * j + 1) * TP + 32 + e];
          p[j] = (a & 0xffffu) | (bv << 16);
        }
        uint4 pv = {p[0], p[1], p[2], p[3]};
        const int n0 = nb + nc * 8;
        const int kt = n0 >> 6, sub = n0 & 63;
        const int ks = sub >> 4, hh = (sub >> 3) & 1;
        const int dt = e >> 5, lv = e & 31;
        *(uint4*)(Vb + (size_t)bb * 262144 +
                  ((((kt * 4 + ks) * 2 + hh) * 2 + dt) * 256 + lv * 8)) = pv;
      }
    }
  }
}

// ---------------------------------------------------------------------------
// Kernel 2: flash attention partials. 1024 blocks (128 q-blocks x 8 segs)
// x 256 thr (4 waves of 32 q). K hi/lo double-buffered via async
// global_load_lds; V direct-from-global B-frags; one barrier per iter.
// ---------------------------------------------------------------------------
#define NSEG 8
#define ITERS 8

__global__ __launch_bounds__(256, 3) void attn_kernel(
    const us* __restrict__ Qhi, const us* __restrict__ Qlo,
    const us* __restrict__ Khi, const us* __restrict__ Klo,
    const us* __restrict__ Vb,
    us* __restrict__ Opart, float* __restrict__ Mpart,
    float* __restrict__ Lpart)
{
  __shared__ union {
    us k[2][2][4096];    // [buf][hi/lo][64 rows x 64 us] = 32,768 B
    float fb[4][2112];   // epilogue bounce, 33,792 B
  } sm;
  __shared__ float alds[4][32];

  // XCD-aware map: XCD x serves batch x>>1
  const int bx = blockIdx.x;
  const int xc = bx & 7, b = xc >> 1;
  const int idx = ((bx >> 3) << 1) | (xc & 1);  // 0..255
  const int seg = idx & (NSEG - 1), qg = idx >> 3;  // seg 0..7, qg 0..31
  const int t = threadIdx.x;
  const int wid = t >> 6, lane = t & 63;
  const int l31 = lane & 31, h = lane >> 5;
  const int q0 = qg * 128 + wid * 32;           // wave's first q
  const int u = (b * 4096 + q0) >> 5;           // global 32q unit, 0..511
  const size_t pb = (size_t)u * NSEG + seg;

  // persistent Q B-frags: n=l31, k=16ks+8h+j
  bf16x8 qh[4], ql[4];
  {
    const size_t rg = (size_t)(b * 4096 + q0 + l31) * 64;
    #pragma unroll
    for (int ks = 0; ks < 4; ++ks) {
      qh[ks] = *(const bf16x8*)(Qhi + rg + ks * 16 + h * 8);
      ql[ks] = *(const bf16x8*)(Qlo + rg + ks * 16 + h * 8);
    }
  }
  const size_t kbase = (size_t)b * 262144;
  const size_t vbb = (size_t)b * 262144;

  // staging map: thread t -> rows (t>>3, +32), 16B slot (t&7), XOR swizzle.
  // LDS byte offset of thread t's chunk = 16*t  -> matches global_load_lds
  // per-wave semantics with wave base = 1024*wid bytes (512 us).
  const int row0 = t >> 3, slot = t & 7;
  const int gcol = (slot ^ (row0 & 7)) * 8;
  const int wb = 512 * wid;                     // wave-uniform LDS base (us)

  // prologue: tile 0 -> buffer 0 (async DMA)
  {
    const int k0 = seg * 512;
    gld16(Khi + kbase + (size_t)(k0 + row0) * 64 + gcol, &sm.k[0][0][wb]);
    gld16(Khi + kbase + (size_t)(k0 + row0 + 32) * 64 + gcol, &sm.k[0][0][wb + 2048]);
    gld16(Klo + kbase + (size_t)(k0 + row0) * 64 + gcol, &sm.k[0][1][wb]);
    gld16(Klo + kbase + (size_t)(k0 + row0 + 32) * 64 + gcol, &sm.k[0][1][wb + 2048]);
  }
  __syncthreads();

  f32x16 o[2] = {};
  float mrun = -__builtin_inff();
  float lrun = 0.f;

  for (int it = 0; it < ITERS; ++it) {
    const int cur = it & 1, nxt = cur ^ 1;
    const int KT = seg * ITERS + it;            // global 64-key tile id

    // async prefetch next K tile into the other buffer (drained by barrier)
    if (it + 1 < ITERS) {
      const int nk = (KT + 1) * 64;
      gld16(Khi + kbase + (size_t)(nk + row0) * 64 + gcol, &sm.k[nxt][0][wb]);
      gld16(Khi + kbase + (size_t)(nk + row0 + 32) * 64 + gcol, &sm.k[nxt][0][wb + 2048]);
      gld16(Klo + kbase + (size_t)(nk + row0) * 64 + gcol, &sm.k[nxt][1][wb]);
      gld16(Klo + kbase + (size_t)(nk + row0 + 32) * 64 + gcol, &sm.k[nxt][1][wb + 2048]);
    }

    // S^T = K_tile · Q^T (3-pass hi/lo): s[m] C-layout rows=keys, cols=q
    f32x16 s[2] = {};
    #pragma unroll
    for (int m = 0; m < 2; ++m) {
      const int krow = 32 * m + l31;
      #pragma unroll
      for (int ks = 0; ks < 4; ++ks) {
        const int off = krow * 64 + (((2 * ks + h) ^ (l31 & 7)) * 8);
        bf16x8 ah = *(const bf16x8*)(&sm.k[cur][0][off]);
        bf16x8 al = *(const bf16x8*)(&sm.k[cur][1][off]);
        s[m] = mfma(ah, qh[ks], s[m]);
        s[m] = mfma(al, qh[ks], s[m]);
        s[m] = mfma(ah, ql[ks], s[m]);
      }
    }

    // online softmax (base-2; scale folded into Q). Lane owns q=l31; holds
    // 32 of its 64 key-scores, partner (xor 32) the rest.
    float vm = -__builtin_inff();
    #pragma unroll
    for (int r = 0; r < 16; ++r)
      vm = fmaxf(vm, fmaxf(s[0][r], s[1][r]));
    vm = fmaxf(vm, __shfl_xor(vm, 32));
    const float mnew = fmaxf(mrun, vm);
    const float alpha = EXP2(mrun - mnew);
    float sum = 0.f;
    unsigned pp[2][8];
    #pragma unroll
    for (int m = 0; m < 2; ++m) {
      #pragma unroll
      for (int p = 0; p < 8; ++p) {
        const float p0 = EXP2(s[m][2 * p] - mnew);
        const float p1 = EXP2(s[m][2 * p + 1] - mnew);
        sum += p0 + p1;
        pp[m][p] = pk2(p0, p1);
      }
    }
    sum += __shfl_xor(sum, 32);
    lrun = lrun * alpha + sum;
    mrun = mnew;

    // rescale O (skip when all-ones; alds broadcast to C-layout rows)
    if (__any(alpha != 1.f)) {
      if (!h) alds[wid][l31] = alpha;
      #pragma unroll
      for (int g = 0; g < 4; ++g) {
        const float4 af4 = *(const float4*)(&alds[wid][8 * g + 4 * h]);
        #pragma unroll
        for (int rr = 0; rr < 4; ++rr) {
          const int r = 4 * g + rr;
          const float a = (rr == 0) ? af4.x : (rr == 1) ? af4.y
                         : (rr == 2) ? af4.z : af4.w;
          o[0][r] *= a;
          o[1][r] *= a;
        }
      }
    }

    // PV: P A-frags via shfl_xor(32) pair exchange; V B-frags from global.
    #pragma unroll
    for (int ks = 0; ks < 4; ++ks) {
      const int m = ks >> 1, base = 4 * (ks & 1);
      const unsigned x0 = pp[m][base + 0], x1 = pp[m][base + 1];
      const unsigned x2 = pp[m][base + 2], x3 = pp[m][base + 3];
      const unsigned sA = h ? x0 : x2;
      const unsigned sB = h ? x1 : x3;
      const unsigned rA = (unsigned)__shfl_xor((int)sA, 32);
      const unsigned rB = (unsigned)__shfl_xor((int)sB, 32);
      u32x4 wv;
      wv.x = h ? rA : x0;
      wv.y = h ? rB : x1;
      wv.z = h ? x2 : rA;
      wv.w = h ? x3 : rB;
      const bf16x8 af = __builtin_bit_cast(bf16x8, wv);
      const size_t vo = vbb + (size_t)((((KT * 4 + ks) * 2 + h) * 2) * 256 + l31 * 8);
      const bf16x8 vf0 = *(const bf16x8*)(Vb + vo);
      const bf16x8 vf1 = *(const bf16x8*)(Vb + vo + 256);
      o[0] = mfma(af, vf0, o[0]);
      o[1] = mfma(af, vf1, o[1]);
    }

    __syncthreads();  // cur reads done; async nxt staging complete
  }

  // epilogue: O -> bf16 Opart via per-wave LDS bounce, dwordx4 stores.
  float* fb = sm.fb[wid];
  #pragma unroll
  for (int dt = 0; dt < 2; ++dt) {
    #pragma unroll
    for (int r = 0; r < 16; ++r) {
      const int qrow = (r & 3) + 8 * (r >> 2) + 4 * h;  // 0..31
      fb[qrow * 66 + l31 + 32 * dt] = o[dt][r];
    }
  }
  #pragma unroll
  for (int jj = 0; jj < 4; ++jj) {
    const int chunk = lane + 64 * jj;           // 0..255
    const int rw = chunk >> 3, part = chunk & 7;
    const float* src = &fb[rw * 66 + part * 8];
    float2 a0 = *(const float2*)(src + 0);
    float2 a1 = *(const float2*)(src + 2);
    float2 a2 = *(const float2*)(src + 4);
    float2 a3 = *(const float2*)(src + 6);
    uint4 pkv;
    pkv.x = pk2(a0.x, a0.y);
    pkv.y = pk2(a1.x, a1.y);
    pkv.z = pk2(a2.x, a2.y);
    pkv.w = pk2(a3.x, a3.y);
    *(uint4*)(Opart + pb * 2048 + (size_t)rw * 64 + part * 8) = pkv;
  }
  if (!h) {
    Mpart[pb * 32 + l31] = mrun;
    Lpart[pb * 32 + l31] = lrun;
  }
}

// ---------------------------------------------------------------------------
// Kernel 3: merge 8 key-segment partials (bf16). 131072 thr, 8 d each.
// ---------------------------------------------------------------------------
__global__ __launch_bounds__(256, 1) void merge_kernel(
    const us* __restrict__ Opart, const float* __restrict__ Mpart,
    const float* __restrict__ Lpart, float* __restrict__ out)
{
  const int tg = blockIdx.x * 256 + threadIdx.x;
  const int q = tg >> 3, dc = (tg & 7) * 8;
  const int u = q >> 5, ql = q & 31;
  const int base = u * NSEG;
  float M = -__builtin_inff();
  #pragma unroll
  for (int s = 0; s < NSEG; ++s)
    M = fmaxf(M, Mpart[(size_t)(base + s) * 32 + ql]);
  float acc[8] = {};
  float den = 0.f;
  #pragma unroll
  for (int s = 0; s < NSEG; ++s) {
    const float wgt = EXP2(Mpart[(size_t)(base + s) * 32 + ql] - M);
    den += wgt * Lpart[(size_t)(base + s) * 32 + ql];
    const uint4 r = *(const uint4*)(Opart + (size_t)(base + s) * 2048 +
                                    ql * 64 + dc);
    const unsigned rw[4] = {r.x, r.y, r.z, r.w};
    #pragma unroll
    for (int j = 0; j < 4; ++j) {
      acc[2 * j]     += wgt * bf2f((us)(rw[j] & 0xffffu));
      acc[2 * j + 1] += wgt * bf2f((us)(rw[j] >> 16));
    }
  }
  const float inv = 1.f / den;
  float4 r0 = {acc[0] * inv, acc[1] * inv, acc[2] * inv, acc[3] * inv};
  float4 r1 = {acc[4] * inv, acc[5] * inv, acc[6] * inv, acc[7] * inv};
  *(float4*)(out + (size_t)q * 64 + dc) = r0;
  *(float4*)(out + (size_t)q * 64 + dc + 4) = r1;
}

// ---------------------------------------------------------------------------
extern "C" void kernel_launch(void* const* d_in, const int* in_sizes, int n_in,
                              void* d_out, int out_size, void* d_ws,
                              size_t ws_size, hipStream_t stream)
{
  const float* x = (const float*)d_in[0];
  const float* w = (const float*)d_in[1];
  float* out = (float*)d_out;
  char* ws = (char*)d_ws;

  const size_t T = 2097152;  // bytes per bf16 [4,4096,64] tensor
  us* Qhi = (us*)(ws + 0 * T);
  us* Qlo = (us*)(ws + 1 * T);
  us* Khi = (us*)(ws + 2 * T);
  us* Klo = (us*)(ws + 3 * T);
  us* Vb  = (us*)(ws + 4 * T);
  us* Wbh = (us*)(ws + 5 * T);                    // 49,152 B
  us* Wbl = (us*)(ws + 5 * T + 49152);            // 49,152 B
  char* pbase = ws + 5 * T + 98304;
  us* Opart = (us*)pbase;                                    // 16,777,216 B
  float* Mpart = (float*)(pbase + 16777216);                 //    524,288 B
  float* Lpart = (float*)(pbase + 16777216 + 524288);        //    524,288 B
  // total workspace use: ~28.4 MiB

  hipLaunchKernelGGL(wprep_kernel, dim3(96), dim3(256), 0, stream, w, Wbh, Wbl);
  hipLaunchKernelGGL(qkv_kernel, dim3(256), dim3(256), 0, stream,
                     x, Wbh, Wbl, Qhi, Qlo, Khi, Klo, Vb);
  hipLaunchKernelGGL(attn_kernel, dim3(1024), dim3(256), 0, stream,
                     Qhi, Qlo, Khi, Klo, Vb, Opart, Mpart, Lpart);
  hipLaunchKernelGGL(merge_kernel, dim3(512), dim3(256), 0, stream,
                     Opart, Mpart, Lpart, out);
}